// Round 3
// baseline (1596.622 us; speedup 1.0000x reference)
//
#include <hip/hip_runtime.h>
#include <hip/hip_bf16.h>
#include <math.h>

#define ICH   3
#define OCH   16
#define ID    18
#define IH    34
#define IW    34
#define OD    16
#define OH    32
#define OW    32
#define NB    128
#define PLANE_W  36                 // padded row stride (16B-aligned float4 at w%4==0)
#define HH       16                 // output rows per block
#define SROWS    (HH + 2)           // 18 staged input rows
#define PLANE_SZ (PLANE_W * SROWS)  // 648 floats per staged plane
#define NPLANES  (ICH * 4)          // 3 ic x 4 d-slices
#define SPATIAL  (OD * OH * OW)     // 16384 per (b,c)
#define EPSV     1e-5f

__device__ __forceinline__ unsigned short f2bf(float f) {
    unsigned int u = __float_as_uint(f);
    unsigned int r = (u + 0x7fffu + ((u >> 16) & 1u)) >> 16;
    return (unsigned short)r;
}
__device__ __forceinline__ float bf2f(unsigned short h) {
    return __uint_as_float(((unsigned int)h) << 16);
}

// Grid: 128 b x 8 dchunk x 2 hhalf = 2048 blocks, 256 threads.
// Waves 0-1: dz=0, waves 2-3: dz=1. Thread: h=(tid>>3)&15, 4 consecutive w.
// oc processed in 2 sequential halves of 8 -> acc[8][4] = 32 live VGPRs (no spills).
// LDS ~31.6 KB -> 5 blocks/CU.
__global__ __launch_bounds__(256, 4) void conv_stats_kernel(
    const float* __restrict__ x, const float* __restrict__ cw,
    const float* __restrict__ cb, const float* __restrict__ mult,
    unsigned short* __restrict__ y, float* __restrict__ stats)
{
    __shared__ float sx[NPLANES][PLANE_SZ];   // 31104 B
    __shared__ float wsum[4][OCH], wsq[4][OCH];

    const int blk = blockIdx.x;
    const int b  = blk >> 4;
    const int r  = blk & 15;
    const int d0 = (r >> 1) * 2;
    const int h0 = (r & 1) * HH;
    const int tid = threadIdx.x;

    // ---- stage 12 planes x 18 rows x 34 cols as float2 ----
    for (int i = tid; i < NPLANES * SROWS * 17; i += 256) {
        const int row   = i / 17;
        const int col2  = (i - row * 17) * 2;
        const int plane = row / SROWS;
        const int prow  = row - plane * SROWS;
        const int ic = plane >> 2, dz = plane & 3;
        const float2 v = *(const float2*)&x[
            ((size_t)(b * ICH + ic) * ID + (d0 + dz)) * (IH * IW)
            + (size_t)(h0 + prow) * IW + col2];
        *(float2*)&sx[plane][prow * PLANE_W + col2] = v;
    }
    __syncthreads();

    const int dz = tid >> 7;         // wave-uniform
    const int h  = (tid >> 3) & 15;
    const int wq = (tid & 7) << 2;
    const int d  = d0 + dz;

#pragma unroll 1
    for (int half = 0; half < 2; half++) {
        const int cbase = half * 8;

        float acc[8][4];
#pragma unroll
        for (int c = 0; c < 8; c++) {
            const float bv = cb[cbase + c];
            acc[c][0] = bv; acc[c][1] = bv; acc[c][2] = bv; acc[c][3] = bv;
        }

#pragma unroll
        for (int ic = 0; ic < ICH; ic++) {
#pragma unroll
            for (int kd = 0; kd < 3; kd++) {
                const float* pl = &sx[ic * 4 + dz + kd][0];
#pragma unroll
                for (int kh = 0; kh < 3; kh++) {
                    const float* row = pl + (h + kh) * PLANE_W + wq;
                    const float4 v0 = *(const float4*)row;
                    const float2 v1 = *(const float2*)(row + 4);
                    float in[6];
                    in[0] = v0.x; in[1] = v0.y; in[2] = v0.z; in[3] = v0.w;
                    in[4] = v1.x; in[5] = v1.y;
                    const int wbase = ic * 27 + kd * 9 + kh * 3;
#pragma unroll
                    for (int kw = 0; kw < 3; kw++) {
#pragma unroll
                        for (int c = 0; c < 8; c++) {
                            const float wv = cw[(cbase + c) * 81 + wbase + kw];
                            acc[c][0] = fmaf(in[kw + 0], wv, acc[c][0]);
                            acc[c][1] = fmaf(in[kw + 1], wv, acc[c][1]);
                            acc[c][2] = fmaf(in[kw + 2], wv, acc[c][2]);
                            acc[c][3] = fmaf(in[kw + 3], wv, acc[c][3]);
                        }
                    }
                }
            }
        }

        // ---- epilogue for this half: mult fold, bf16 store, stats reduce ----
#pragma unroll
        for (int c = 0; c < 8; c++) {
            const float m = mult[cbase + c];
            const float o0 = acc[c][0] * m, o1 = acc[c][1] * m;
            const float o2 = acc[c][2] * m, o3 = acc[c][3] * m;
            float s = (o0 + o1) + (o2 + o3);
            float q = (o0 * o0 + o1 * o1) + (o2 * o2 + o3 * o3);
            const size_t yi = ((size_t)(b * OCH + cbase + c) * OD + d) * (OH * OW)
                              + (size_t)(h0 + h) * OW + wq;
            ushort4 pk;
            pk.x = f2bf(o0); pk.y = f2bf(o1); pk.z = f2bf(o2); pk.w = f2bf(o3);
            *(ushort4*)&y[yi] = pk;
            for (int off = 32; off > 0; off >>= 1) {
                s += __shfl_down(s, off);
                q += __shfl_down(q, off);
            }
            if ((tid & 63) == 0) {
                wsum[tid >> 6][cbase + c] = s;
                wsq[tid >> 6][cbase + c]  = q;
            }
        }
    }

    __syncthreads();
    if (tid < OCH) {
        float s = 0.0f, q = 0.0f;
#pragma unroll
        for (int k = 0; k < 4; k++) { s += wsum[k][tid]; q += wsq[k][tid]; }
        atomicAdd(&stats[(b * OCH + tid) * 2 + 0], s);
        atomicAdd(&stats[(b * OCH + tid) * 2 + 1], q);
    }
}

// Grid: 128 b x 8 segments = 1024 blocks. Each thread: 8 consecutive positions
// (one 16B load per channel), 16 channels.
__global__ __launch_bounds__(256) void norm_max_kernel(
    const unsigned short* __restrict__ y, const float* __restrict__ stats,
    const float* __restrict__ mult, float* __restrict__ out)
{
    const int blk = blockIdx.x;
    const int b   = blk >> 3;
    const int seg = blk & 7;
    const int tid = threadIdx.x;

    __shared__ float srs[OCH], snb[OCH], smul[OCH];
    if (tid < OCH) {
        const float s  = stats[(b * OCH + tid) * 2 + 0];
        const float sq = stats[(b * OCH + tid) * 2 + 1];
        const float mean = s * (1.0f / (float)SPATIAL);
        float var = sq * (1.0f / (float)SPATIAL) - mean * mean;
        var = fmaxf(var, 0.0f);
        const float rs = rsqrtf(var + EPSV);
        srs[tid]  = rs;
        snb[tid]  = -mean * rs;       // normalized = v*rs + nb
        smul[tid] = mult[tid];
    }
    __syncthreads();

    const size_t ybase = (size_t)b * OCH * SPATIAL;
    const int s = seg * 2048 + tid * 8;

    float best[8];
#pragma unroll
    for (int j = 0; j < 8; j++) best[j] = -INFINITY;

#pragma unroll
    for (int c = 0; c < OCH; c++) {
        const uint4 v = *(const uint4*)&y[ybase + (size_t)c * SPATIAL + s];
        const float rs = srs[c], nb = snb[c], m = smul[c];
        const unsigned int u[4] = {v.x, v.y, v.z, v.w};
#pragma unroll
        for (int p = 0; p < 4; p++) {
            float f0 = __uint_as_float(u[p] << 16)          * rs + nb;
            float f1 = __uint_as_float(u[p] & 0xffff0000u)  * rs + nb;
            f0 = fminf(fmaxf(f0, -1.0f), 1.0f) * m;
            f1 = fminf(fmaxf(f1, -1.0f), 1.0f) * m;
            best[2 * p + 0] = fmaxf(best[2 * p + 0], f0);
            best[2 * p + 1] = fmaxf(best[2 * p + 1], f1);
        }
    }

    float* op = &out[(size_t)b * SPATIAL + s];
    float4 o0; o0.x = best[0]; o0.y = best[1]; o0.z = best[2]; o0.w = best[3];
    float4 o1; o1.x = best[4]; o1.y = best[5]; o1.z = best[6]; o1.w = best[7];
    *(float4*)op = o0;
    *(float4*)(op + 4) = o1;
}

extern "C" void kernel_launch(void* const* d_in, const int* in_sizes, int n_in,
                              void* d_out, int out_size, void* d_ws, size_t ws_size,
                              hipStream_t stream) {
    const float* x    = (const float*)d_in[0];
    const float* cw   = (const float*)d_in[1];
    const float* cb   = (const float*)d_in[2];
    const float* mult = (const float*)d_in[3];
    float* out = (float*)d_out;

    unsigned short* y = (unsigned short*)d_ws;
    float* stats = (float*)((char*)d_ws + (size_t)NB * OCH * SPATIAL * sizeof(unsigned short));

    hipMemsetAsync(stats, 0, (size_t)NB * OCH * 2 * sizeof(float), stream);
    conv_stats_kernel<<<NB * 16, 256, 0, stream>>>(x, cw, cb, mult, y, stats);
    norm_max_kernel<<<NB * 8, 256, 0, stream>>>(y, stats, mult, out);
}

// Round 4
// 196.879 us; speedup vs baseline: 8.1096x; 8.1096x over previous
//
#include <hip/hip_runtime.h>
#include <hip/hip_bf16.h>
#include <math.h>

#define ICH   3
#define OCH   16
#define ID    18
#define IH    34
#define IW    34
#define OD    16
#define OH    32
#define OW    32
#define NB    128
#define PLANE_W  36                 // padded row stride (16B-aligned float4 at w%4==0)
#define HH       16                 // output rows per block
#define SROWS    (HH + 2)           // 18 staged input rows
#define PLANE_SZ (PLANE_W * SROWS)  // 648 floats per staged plane
#define NPLANES  (ICH * 4)          // 3 ic x 4 d-slices
#define SPATIAL  (OD * OH * OW)     // 16384 per (b,c)
#define EPSV     1e-5f

__device__ __forceinline__ unsigned short f2bf(float f) {
    unsigned int u = __float_as_uint(f);
    unsigned int r = (u + 0x7fffu + ((u >> 16) & 1u)) >> 16;
    return (unsigned short)r;
}

// Grid: 128 b x 8 dchunk x 2 hhalf = 2048 blocks, 256 threads.
// Waves 0-1: dz=0, waves 2-3: dz=1. Thread: h=(tid>>3)&15, 4 consecutive w,
// all 16 oc in one fully-unrolled pass (weight indices compile-time -> s_load).
// LDS 31.6 KB + VGPR ~88 -> 5 blocks/CU (20 waves).
// NOTE: do NOT raise min-waves in __launch_bounds__ — (256,4)/(256,5) force
// VGPR to 64/48 and spill to scratch (R2/R3 regression: WRITE_SIZE +40..850 MB).
__global__ __launch_bounds__(256, 2) void conv_stats_kernel(
    const float* __restrict__ x, const float* __restrict__ cw,
    const float* __restrict__ cb, const float* __restrict__ mult,
    unsigned short* __restrict__ y, float* __restrict__ stats)
{
    __shared__ float sx[NPLANES][PLANE_SZ];   // 31104 B
    __shared__ float wsum[4][OCH], wsq[4][OCH];

    const int blk = blockIdx.x;
    const int b  = blk >> 4;
    const int r  = blk & 15;
    const int d0 = (r >> 1) * 2;
    const int h0 = (r & 1) * HH;
    const int tid = threadIdx.x;

    // ---- stage 12 planes x 18 rows x 34 cols as float2 ----
    for (int i = tid; i < NPLANES * SROWS * 17; i += 256) {
        const int row   = i / 17;
        const int col2  = (i - row * 17) * 2;
        const int plane = row / SROWS;
        const int prow  = row - plane * SROWS;
        const int ic = plane >> 2, dz = plane & 3;
        const float2 v = *(const float2*)&x[
            ((size_t)(b * ICH + ic) * ID + (d0 + dz)) * (IH * IW)
            + (size_t)(h0 + prow) * IW + col2];
        *(float2*)&sx[plane][prow * PLANE_W + col2] = v;
    }
    __syncthreads();

    const int dz = tid >> 7;         // wave-uniform
    const int h  = (tid >> 3) & 15;
    const int wq = (tid & 7) << 2;
    const int d  = d0 + dz;

    float acc[OCH][4];
#pragma unroll
    for (int c = 0; c < OCH; c++) {
        const float bv = cb[c];
        acc[c][0] = bv; acc[c][1] = bv; acc[c][2] = bv; acc[c][3] = bv;
    }

#pragma unroll
    for (int ic = 0; ic < ICH; ic++) {
#pragma unroll
        for (int kd = 0; kd < 3; kd++) {
            const float* pl = &sx[ic * 4 + dz + kd][0];
#pragma unroll
            for (int kh = 0; kh < 3; kh++) {
                const float* row = pl + (h + kh) * PLANE_W + wq;
                const float4 v0 = *(const float4*)row;
                const float2 v1 = *(const float2*)(row + 4);
                float in[6];
                in[0] = v0.x; in[1] = v0.y; in[2] = v0.z; in[3] = v0.w;
                in[4] = v1.x; in[5] = v1.y;
                const int wbase = ic * 27 + kd * 9 + kh * 3;
#pragma unroll
                for (int kw = 0; kw < 3; kw++) {
#pragma unroll
                    for (int c = 0; c < OCH; c++) {
                        const float wv = cw[c * 81 + wbase + kw];  // compile-time idx -> s_load
                        acc[c][0] = fmaf(in[kw + 0], wv, acc[c][0]);
                        acc[c][1] = fmaf(in[kw + 1], wv, acc[c][1]);
                        acc[c][2] = fmaf(in[kw + 2], wv, acc[c][2]);
                        acc[c][3] = fmaf(in[kw + 3], wv, acc[c][3]);
                    }
                }
            }
        }
    }

    // ---- multiplier fold, stats, bf16 store ----
    float ssum[OCH], ssq[OCH];
#pragma unroll
    for (int c = 0; c < OCH; c++) {
        const float m = mult[c];
        const float o0 = acc[c][0] * m, o1 = acc[c][1] * m;
        const float o2 = acc[c][2] * m, o3 = acc[c][3] * m;
        ssum[c] = (o0 + o1) + (o2 + o3);
        ssq[c]  = (o0 * o0 + o1 * o1) + (o2 * o2 + o3 * o3);
        const size_t yi = ((size_t)(b * OCH + c) * OD + d) * (OH * OW)
                          + (size_t)(h0 + h) * OW + wq;
        ushort4 pk;
        pk.x = f2bf(o0); pk.y = f2bf(o1); pk.z = f2bf(o2); pk.w = f2bf(o3);
        *(ushort4*)&y[yi] = pk;
    }

    // ---- block reduction of stats, one atomicAdd per (b,c) ----
#pragma unroll
    for (int c = 0; c < OCH; c++) {
        for (int off = 32; off > 0; off >>= 1) {
            ssum[c] += __shfl_down(ssum[c], off);
            ssq[c]  += __shfl_down(ssq[c], off);
        }
    }
    const int wave = tid >> 6, lane = tid & 63;
    if (lane == 0) {
#pragma unroll
        for (int c = 0; c < OCH; c++) { wsum[wave][c] = ssum[c]; wsq[wave][c] = ssq[c]; }
    }
    __syncthreads();
    if (tid < OCH) {
        float s = 0.0f, q = 0.0f;
#pragma unroll
        for (int k = 0; k < 4; k++) { s += wsum[k][tid]; q += wsq[k][tid]; }
        atomicAdd(&stats[(b * OCH + tid) * 2 + 0], s);
        atomicAdd(&stats[(b * OCH + tid) * 2 + 1], q);
    }
}

// Grid: 128 b x 8 segments = 1024 blocks. Each thread: 8 consecutive positions
// (one 16B load per channel), 16 channels.
__global__ __launch_bounds__(256) void norm_max_kernel(
    const unsigned short* __restrict__ y, const float* __restrict__ stats,
    const float* __restrict__ mult, float* __restrict__ out)
{
    const int blk = blockIdx.x;
    const int b   = blk >> 3;
    const int seg = blk & 7;
    const int tid = threadIdx.x;

    __shared__ float srs[OCH], snb[OCH], smul[OCH];
    if (tid < OCH) {
        const float s  = stats[(b * OCH + tid) * 2 + 0];
        const float sq = stats[(b * OCH + tid) * 2 + 1];
        const float mean = s * (1.0f / (float)SPATIAL);
        float var = sq * (1.0f / (float)SPATIAL) - mean * mean;
        var = fmaxf(var, 0.0f);
        const float rs = rsqrtf(var + EPSV);
        srs[tid]  = rs;
        snb[tid]  = -mean * rs;       // normalized = v*rs + nb
        smul[tid] = mult[tid];
    }
    __syncthreads();

    const size_t ybase = (size_t)b * OCH * SPATIAL;
    const int s = seg * 2048 + tid * 8;

    float best[8];
#pragma unroll
    for (int j = 0; j < 8; j++) best[j] = -INFINITY;

#pragma unroll
    for (int c = 0; c < OCH; c++) {
        const uint4 v = *(const uint4*)&y[ybase + (size_t)c * SPATIAL + s];
        const float rs = srs[c], nb = snb[c], m = smul[c];
        const unsigned int u[4] = {v.x, v.y, v.z, v.w};
#pragma unroll
        for (int p = 0; p < 4; p++) {
            float f0 = __uint_as_float(u[p] << 16)          * rs + nb;
            float f1 = __uint_as_float(u[p] & 0xffff0000u)  * rs + nb;
            f0 = fminf(fmaxf(f0, -1.0f), 1.0f) * m;
            f1 = fminf(fmaxf(f1, -1.0f), 1.0f) * m;
            best[2 * p + 0] = fmaxf(best[2 * p + 0], f0);
            best[2 * p + 1] = fmaxf(best[2 * p + 1], f1);
        }
    }

    float* op = &out[(size_t)b * SPATIAL + s];
    float4 o0; o0.x = best[0]; o0.y = best[1]; o0.z = best[2]; o0.w = best[3];
    float4 o1; o1.x = best[4]; o1.y = best[5]; o1.z = best[6]; o1.w = best[7];
    *(float4*)op = o0;
    *(float4*)(op + 4) = o1;
}

extern "C" void kernel_launch(void* const* d_in, const int* in_sizes, int n_in,
                              void* d_out, int out_size, void* d_ws, size_t ws_size,
                              hipStream_t stream) {
    const float* x    = (const float*)d_in[0];
    const float* cw   = (const float*)d_in[1];
    const float* cb   = (const float*)d_in[2];
    const float* mult = (const float*)d_in[3];
    float* out = (float*)d_out;

    unsigned short* y = (unsigned short*)d_ws;
    float* stats = (float*)((char*)d_ws + (size_t)NB * OCH * SPATIAL * sizeof(unsigned short));

    hipMemsetAsync(stats, 0, (size_t)NB * OCH * 2 * sizeof(float), stream);
    conv_stats_kernel<<<NB * 16, 256, 0, stream>>>(x, cw, cb, mult, y, stats);
    norm_max_kernel<<<NB * 8, 256, 0, stream>>>(y, stats, mult, out);
}